// Round 11
// baseline (502.808 us; speedup 1.0000x reference)
//
#include <hip/hip_runtime.h>

#define NN 10000
#define NPAD 10048
#define EE 128000
#define ETOT 138000
#define DD 256
#define DIN 64

typedef unsigned short u16;
typedef __attribute__((ext_vector_type(8))) short short8v;
typedef __attribute__((ext_vector_type(4))) short short4v;
typedef __attribute__((ext_vector_type(4))) float f32x4;

__device__ __forceinline__ u16 f2bf(float f) {
    union { float f; unsigned u; } a; a.f = f;
    unsigned r = a.u + 0x7fffu + ((a.u >> 16) & 1u);
    return (u16)(r >> 16);
}
__device__ __forceinline__ float bf2f(u16 b) {
    union { unsigned u; float f; } a; a.u = ((unsigned)b) << 16;
    return a.f;
}

__device__ __forceinline__ void gl2lds16(const void* g, void* l) {
    __builtin_amdgcn_global_load_lds((const __attribute__((address_space(1))) unsigned int*)g,
                                     (__attribute__((address_space(3))) unsigned int*)l, 16, 0, 0);
}

// ---------------- weight/input split kernels ----------------

__global__ void split_k(const float* __restrict__ W, u16* __restrict__ H, u16* __restrict__ L, int total) {
    int i = blockIdx.x * 256 + threadIdx.x;
    if (i >= total) return;
    float f = W[i];
    u16 h = f2bf(f);
    H[i] = h;
    L[i] = f2bf(f - bf2f(h));
}

__global__ void cvt_k(const float* __restrict__ W, u16* __restrict__ H, int total) {
    int i = blockIdx.x * 256 + threadIdx.x;
    if (i >= total) return;
    H[i] = f2bf(W[i]);
}

__global__ void transpose_split_k(const float* __restrict__ W, u16* __restrict__ H, u16* __restrict__ L,
                                  int R, int C) {
    int idx = blockIdx.x * 256 + threadIdx.x;
    if (idx >= R * C) return;
    int r = idx / C, c = idx % C;
    float f = W[idx];
    u16 h = f2bf(f);
    H[c * R + r] = h;
    L[c * R + r] = f2bf(f - bf2f(h));
}

// ---------------- CSR build ----------------

__global__ void deg_k(const int* __restrict__ ei, int* __restrict__ deg, int E, int Etot) {
    int e = blockIdx.x * 256 + threadIdx.x;
    if (e >= Etot) return;
    int dn = (e < E) ? ei[E + e] : (e - E);
    atomicAdd(&deg[dn], 1);
}

__global__ __launch_bounds__(1024) void scan_k(const int* __restrict__ deg, int* __restrict__ offs,
                                               int* __restrict__ cursor, int Nn) {
    __shared__ int ps[1024];
    int t = threadIdx.x;
    int chunk = (Nn + 1023) >> 10;
    int i0 = t * chunk;
    int local = 0;
    for (int i = 0; i < chunk; i++) {
        int idx = i0 + i;
        if (idx < Nn) local += deg[idx];
    }
    ps[t] = local;
    __syncthreads();
    for (int off = 1; off < 1024; off <<= 1) {
        int v = 0;
        if (t >= off) v = ps[t - off];
        __syncthreads();
        if (t >= off) ps[t] += v;
        __syncthreads();
    }
    int run = ps[t] - local;
    for (int i = 0; i < chunk; i++) {
        int idx = i0 + i;
        if (idx < Nn) {
            offs[idx] = run;
            cursor[idx] = run;
            run += deg[idx];
        }
    }
}

__global__ void csr_fill_k(const int* __restrict__ ei, int* __restrict__ cursor,
                           int* __restrict__ csr_eid, int* __restrict__ csr_src, int E, int Etot) {
    int e = blockIdx.x * 256 + threadIdx.x;
    if (e >= Etot) return;
    int s, dn;
    if (e < E) { s = ei[e]; dn = ei[E + e]; }
    else { s = dn = e - E; }
    int pos = atomicAdd(&cursor[dn], 1);
    csr_eid[pos] = e;
    csr_src[pos] = s;
}

// ---------------- GAT score path ----------------

__global__ __launch_bounds__(256) void edge_scores_max_k(
    const int* __restrict__ ei, const float* __restrict__ asrc, const float* __restrict__ adst,
    float* __restrict__ sc, float* __restrict__ pmax, int E, int Etot) {
    int t = threadIdx.x;
    int total = Etot * 4;
    int gid = blockIdx.x * 256 + t;
    int stride = gridDim.x * 256;
    float m = -3.4e38f;
    for (int idx = gid; idx < total; idx += stride) {
        int e = idx >> 2, hd = idx & 3;
        int s, dn;
        if (e < E) { s = ei[e]; dn = ei[E + e]; }
        else { s = dn = e - E; }
        float v = asrc[s * 4 + hd] + adst[dn * 4 + hd];
        sc[idx] = v;
        m = fmaxf(m, v);
    }
    __shared__ float lds[256];
    lds[t] = m;
    __syncthreads();
    if (t < 4) {
        float r = -3.4e38f;
        for (int j = t; j < 256; j += 4) r = fmaxf(r, lds[j]);
        pmax[blockIdx.x * 4 + t] = r;
    }
}

__global__ __launch_bounds__(256) void exp_sum_k(float* __restrict__ sc, const float* __restrict__ pmax,
                                                 float* __restrict__ hsum, int total) {
    __shared__ float red[256];
    __shared__ float hm[4];
    __shared__ float ls[4];
    int t = threadIdx.x;
    float m = -3.4e38f;
    for (int j = t; j < 1024; j += 256) m = fmaxf(m, pmax[j]);
    red[t] = m;
    if (t < 4) ls[t] = 0.f;
    __syncthreads();
    if (t < 4) {
        float r = -3.4e38f;
        for (int j = t; j < 256; j += 4) r = fmaxf(r, red[j]);
        hm[t] = r;
    }
    __syncthreads();
    int idx = blockIdx.x * 256 + t;
    if (idx < total) {
        int hd = idx & 3;
        float w = expf(sc[idx] - hm[hd]);
        sc[idx] = w;
        atomicAdd(&ls[hd], w);
    }
    __syncthreads();
    if (t < 4) atomicAdd(&hsum[t], ls[t]);
}

// ---------------- feature-sliced gather aggregation ----------------
// grid (Nn/4, 4): blockIdx.y = p selects head p and feature slice [64p, 64p+64).
// wave = node (4 nodes/block); lane -> (view v = l>>4, fgroup fg = l&15, feats 4fg..4fg+3 of slice).
// Per-pass working set of hB = 5.1 MB -> per-XCD L2 resident. Edge weight is wave-uniform.
__global__ __launch_bounds__(256) void agg4_k(const u16* __restrict__ hB, const float* __restrict__ wts,
                                              const int* __restrict__ offs, const int* __restrict__ deg,
                                              const int* __restrict__ csr_eid, const int* __restrict__ csr_src,
                                              const float* __restrict__ hsum,
                                              u16* __restrict__ aggH, u16* __restrict__ aggL, int Nn) {
    int wv = threadIdx.x >> 6, lane = threadIdx.x & 63;
    int n = blockIdx.x * 4 + wv;
    int p = blockIdx.y;
    if (n >= Nn) return;
    float inv = 1.0f / hsum[p];
    int v = lane >> 4, fg = lane & 15;
    const long fb = (long)p * 64 + fg * 4;
    const long vboff = (long)v * 256 + fb;
    int o0 = offs[n], dg = deg[n];
    float a0 = 0.f, a1 = 0.f, a2 = 0.f, a3 = 0.f;
    int q = 0;
    for (; q + 1 < dg; q += 2) {
        int e0 = csr_eid[o0 + q], e1 = csr_eid[o0 + q + 1];
        int s0 = csr_src[o0 + q], s1 = csr_src[o0 + q + 1];
        float w0 = wts[e0 * 4 + p] * inv;
        float w1 = wts[e1 * 4 + p] * inv;
        short4v h0 = *(const short4v*)&hB[(long)s0 * 1024 + vboff];
        short4v h1 = *(const short4v*)&hB[(long)s1 * 1024 + vboff];
        a0 += w0 * bf2f((u16)h0[0]) + w1 * bf2f((u16)h1[0]);
        a1 += w0 * bf2f((u16)h0[1]) + w1 * bf2f((u16)h1[1]);
        a2 += w0 * bf2f((u16)h0[2]) + w1 * bf2f((u16)h1[2]);
        a3 += w0 * bf2f((u16)h0[3]) + w1 * bf2f((u16)h1[3]);
    }
    if (q < dg) {
        int e0 = csr_eid[o0 + q];
        int s0 = csr_src[o0 + q];
        float w0 = wts[e0 * 4 + p] * inv;
        short4v h0 = *(const short4v*)&hB[(long)s0 * 1024 + vboff];
        a0 += w0 * bf2f((u16)h0[0]);
        a1 += w0 * bf2f((u16)h0[1]);
        a2 += w0 * bf2f((u16)h0[2]);
        a3 += w0 * bf2f((u16)h0[3]);
    }
    union { short4v v4; u16 u[4]; } oh, ol;
    float av[4] = {a0, a1, a2, a3};
#pragma unroll
    for (int c = 0; c < 4; c++) {
        u16 hb = f2bf(av[c]);
        oh.u[c] = hb;
        ol.u[c] = f2bf(av[c] - bf2f(hb));
    }
    long ob = ((long)v * NPAD + n) * 256 + fb;
    *(short4v*)&aggH[ob] = oh.v4;
    *(short4v*)&aggL[ob] = ol.v4;
}

// ---------------- pipelined 1-term bf16 h-GEMM, wave-local repack + fused att-scores ----------------
template <int KK>
__global__ __launch_bounds__(256) void gemm_h(
    const u16* __restrict__ AH, const u16* __restrict__ BH,
    u16* __restrict__ CH, int M, int Nnodes,
    const float* __restrict__ attw, float* __restrict__ asrc, float* __restrict__ adst, int nwg) {
    __shared__ __attribute__((aligned(16))) u16 S[16384];  // 32 KB flat
    int orig = blockIdx.y * 2 + blockIdx.x;
    int qq = nwg >> 3, rr = nwg & 7;
    int xcd = orig & 7, pos = orig >> 3;
    int wg = (xcd < rr ? xcd * (qq + 1) : rr * (qq + 1) + (xcd - rr) * qq) + pos;
    int bx = wg & 1, by = wg >> 1;
    int row0 = by * 128, col0 = bx * 128;
    int t = threadIdx.x, lane = t & 63, wv = t >> 6;

    int d0 = (wv * 2) * 64 + lane, d1 = d0 + 64;
    int row_0 = d0 >> 2, gp_0 = d0 & 3;
    int row_1 = d1 >> 2, gp_1 = d1 & 3;
    int sw_0 = (gp_0 ^ ((row_0 >> 1) & 3)) << 3;
    int sw_1 = (gp_1 ^ ((row_1 >> 1) & 3)) << 3;
    long arow0 = (long)(row0 + row_0) * KK + sw_0;
    long arow1 = (long)(row0 + row_1) * KK + sw_1;
    long brow0 = (long)(col0 + row_0) * KK + sw_0;
    long brow1 = (long)(col0 + row_1) * KK + sw_1;
    int base0 = wv * 1024, base1 = base0 + 512;

    int wr = wv >> 1, wc = wv & 1, lm = lane & 15, lk = lane >> 4;
    const int gsw = (lk ^ ((lm >> 1) & 3)) * 8;

    f32x4 acc[4][4];
#pragma unroll
    for (int i = 0; i < 4; i++)
#pragma unroll
        for (int j = 0; j < 4; j++) acc[i][j] = (f32x4)(0.f);

#define STAGE_H(db, k0)                                               \
    do {                                                              \
        gl2lds16(AH + arow0 + (k0), &S[(db) * 8192 + base0]);         \
        gl2lds16(BH + brow0 + (k0), &S[(db) * 8192 + 4096 + base0]);  \
        gl2lds16(AH + arow1 + (k0), &S[(db) * 8192 + base1]);         \
        gl2lds16(BH + brow1 + (k0), &S[(db) * 8192 + 4096 + base1]);  \
    } while (0)

    STAGE_H(0, 0);
#pragma unroll
    for (int ks = 0; ks < KK / 32; ks++) {
        int cur = ks & 1;
        if (ks < KK / 32 - 1) {
            STAGE_H(cur ^ 1, (ks + 1) * 32);
            asm volatile("s_waitcnt vmcnt(4)" ::: "memory");
        } else {
            asm volatile("s_waitcnt vmcnt(0)" ::: "memory");
        }
        __builtin_amdgcn_s_barrier();
        asm volatile("" ::: "memory");
        const u16* AhS = S + cur * 8192;
        const u16* BhS = S + cur * 8192 + 4096;
        short8v af[4], bf[4];
#pragma unroll
        for (int i = 0; i < 4; i++) {
            af[i] = *(const short8v*)&AhS[(wr * 64 + i * 16 + lm) * 32 + gsw];
            bf[i] = *(const short8v*)&BhS[(wc * 64 + i * 16 + lm) * 32 + gsw];
        }
#pragma unroll
        for (int i = 0; i < 4; i++)
#pragma unroll
            for (int j = 0; j < 4; j++)
                acc[i][j] = __builtin_amdgcn_mfma_f32_16x16x32_bf16(af[i], bf[j], acc[i][j], 0, 0, 0);
        asm volatile("" ::: "memory");
        __builtin_amdgcn_s_barrier();
    }
#undef STAGE_H

    // ---- wave-local repack epilogue ----
    {
        u16* T = &S[wv * 4096];
#pragma unroll
        for (int i = 0; i < 4; i++)
#pragma unroll
            for (int j = 0; j < 4; j++) {
                int colb = j * 16 + lm;
#pragma unroll
                for (int r = 0; r < 4; r++) {
                    int rowT = i * 16 + lk * 4 + r;
                    T[rowT * 64 + (colb ^ ((rowT & 7) << 3))] = f2bf(acc[i][j][r]);
                }
            }
        __builtin_amdgcn_sched_barrier(0);
#pragma unroll
        for (int it = 0; it < 8; it++) {
            int idx = lane + it * 64;
            int row = idx >> 3, colg = (idx & 7) * 8;
            short8v val = *(const short8v*)&T[row * 64 + (colg ^ ((row & 7) << 3))];
            int mrow = row0 + wr * 64 + row;
            if (mrow < M) {
                int vv = mrow / Nnodes;
                int n = mrow - vv * Nnodes;
                *(short8v*)&CH[((long)n * 4 + vv) * 256 + col0 + wc * 64 + colg] = val;
            }
        }
    }

    // fused GAT attention scores (register-only)
    {
        int hd = (col0 >> 6) + wc;
        const float* attS = attw + hd * 128;
        const float* attD = attS + 64;
#pragma unroll
        for (int i = 0; i < 4; i++) {
            int rowb = row0 + wr * 64 + i * 16 + lk * 4;
#pragma unroll
            for (int r = 0; r < 4; r++) {
                int mrow = rowb + r;
                float sS = 0.f, sD = 0.f;
#pragma unroll
                for (int j = 0; j < 4; j++) {
                    float hv2 = acc[i][j][r];
                    float hl = hv2 > 0.f ? hv2 : 0.2f * hv2;
                    int f = j * 16 + lm;
                    sS += hl * attS[f];
                    sD += hl * attD[f];
                }
#pragma unroll
                for (int msk = 1; msk < 16; msk <<= 1) {
                    sS += __shfl_xor(sS, msk, 64);
                    sD += __shfl_xor(sD, msk, 64);
                }
                if (lm == 0 && mrow < M) {
                    int vv = mrow / Nnodes;
                    int n = mrow - vv * Nnodes;
                    atomicAdd(&asrc[n * 4 + hd], 0.25f * sS);
                    atomicAdd(&adst[n * 4 + hd], 0.25f * sD);
                }
            }
        }
    }
}

// ---------------- pipelined single-bf16 QK GEMM, wave-local repack ----------------
__global__ __launch_bounds__(256) void gemm_qk(
    const u16* __restrict__ AH, const u16* __restrict__ BH,
    const float* __restrict__ bias, u16* __restrict__ QK,
    int Mc, int nodeBase, int nwg) {
    __shared__ __attribute__((aligned(16))) u16 S[16384];
    int orig = blockIdx.y * 4 + blockIdx.x;
    int qq = nwg >> 3, rr = nwg & 7;
    int xcd = orig & 7, pos = orig >> 3;
    int wg = (xcd < rr ? xcd * (qq + 1) : rr * (qq + 1) + (xcd - rr) * qq) + pos;
    int bx = wg & 3, by = wg >> 2;
    int row0 = by * 128, col0 = bx * 128;
    int t = threadIdx.x, lane = t & 63, wv = t >> 6;

    int d0 = (wv * 2) * 64 + lane, d1 = d0 + 64;
    int row_0 = d0 >> 2, gp_0 = d0 & 3;
    int row_1 = d1 >> 2, gp_1 = d1 & 3;
    int sw_0 = (gp_0 ^ ((row_0 >> 1) & 3)) << 3;
    int sw_1 = (gp_1 ^ ((row_1 >> 1) & 3)) << 3;
    int m_0 = row0 + row_0, m_1 = row0 + row_1;
    long arow0 = ((long)(m_0 & 3) * NPAD + nodeBase + (m_0 >> 2)) * 256 + sw_0;
    long arow1 = ((long)(m_1 & 3) * NPAD + nodeBase + (m_1 >> 2)) * 256 + sw_1;
    long brow0 = (long)(col0 + row_0) * 256 + sw_0;
    long brow1 = (long)(col0 + row_1) * 256 + sw_1;
    int base0 = wv * 1024, base1 = base0 + 512;

    int wr = wv >> 1, wc = wv & 1, lm = lane & 15, lk = lane >> 4;
    const int gsw = (lk ^ ((lm >> 1) & 3)) * 8;

    f32x4 acc[4][4];
#pragma unroll
    for (int i = 0; i < 4; i++)
#pragma unroll
        for (int j = 0; j < 4; j++) acc[i][j] = (f32x4)(0.f);

#define STAGE_QK(db, k0)                                              \
    do {                                                              \
        gl2lds16(AH + arow0 + (k0), &S[(db) * 8192 + base0]);         \
        gl2lds16(BH + brow0 + (k0), &S[(db) * 8192 + 4096 + base0]);  \
        gl2lds16(AH + arow1 + (k0), &S[(db) * 8192 + base1]);         \
        gl2lds16(BH + brow1 + (k0), &S[(db) * 8192 + 4096 + base1]);  \
    } while (0)

    STAGE_QK(0, 0);
    for (int ks = 0; ks < 8; ks++) {
        int cur = ks & 1;
        if (ks < 7) {
            STAGE_QK(cur ^ 1, (ks + 1) * 32);
            asm volatile("s_waitcnt vmcnt(4)" ::: "memory");
        } else {
            asm volatile("s_waitcnt vmcnt(0)" ::: "memory");
        }
        __builtin_amdgcn_s_barrier();
        asm volatile("" ::: "memory");
        const u16* AhS = S + cur * 8192;
        const u16* BhS = S + cur * 8192 + 4096;
        short8v af[4], bf[4];
#pragma unroll
        for (int i = 0; i < 4; i++) {
            af[i] = *(const short8v*)&AhS[(wr * 64 + i * 16 + lm) * 32 + gsw];
            bf[i] = *(const short8v*)&BhS[(wc * 64 + i * 16 + lm) * 32 + gsw];
        }
#pragma unroll
        for (int i = 0; i < 4; i++)
#pragma unroll
            for (int j = 0; j < 4; j++)
                acc[i][j] = __builtin_amdgcn_mfma_f32_16x16x32_bf16(af[i], bf[j], acc[i][j], 0, 0, 0);
        asm volatile("" ::: "memory");
        __builtin_amdgcn_s_barrier();
    }
#undef STAGE_QK

    // ---- wave-local repack epilogue ----
    {
        u16* T = &S[wv * 4096];
#pragma unroll
        for (int i = 0; i < 4; i++)
#pragma unroll
            for (int j = 0; j < 4; j++) {
                int colb = j * 16 + lm;
                float bb = bias[col0 + wc * 64 + colb];
#pragma unroll
                for (int r = 0; r < 4; r++) {
                    int rowT = i * 16 + lk * 4 + r;
                    T[rowT * 64 + (colb ^ ((rowT & 7) << 3))] = f2bf(acc[i][j][r] + bb);
                }
            }
        __builtin_amdgcn_sched_barrier(0);
#pragma unroll
        for (int it = 0; it < 8; it++) {
            int idx = lane + it * 64;
            int row = idx >> 3, colg = (idx & 7) * 8;
            short8v val = *(const short8v*)&T[row * 64 + (colg ^ ((row & 7) << 3))];
            int mrow = row0 + wr * 64 + row;
            if (mrow < Mc) *(short8v*)&QK[(long)mrow * 512 + col0 + wc * 64 + colg] = val;
        }
    }
}

// ---------------- pipelined 3-term V GEMM with fused PV + wave-local repack ----------------
__global__ __launch_bounds__(256) void gemm_vpv(
    const u16* __restrict__ AH, const u16* __restrict__ AL,
    const u16* __restrict__ BH, const u16* __restrict__ BL,
    const float* __restrict__ biasV, const float* __restrict__ aw,
    u16* __restrict__ PVH, u16* __restrict__ PVL,
    int Mc, int nodeBase, int nwg) {
    __shared__ __attribute__((aligned(16))) u16 S[32768];  // 64 KB flat
    __shared__ float awS[1024];
    int orig = blockIdx.y * 2 + blockIdx.x;
    int qq = nwg >> 3, rr = nwg & 7;
    int xcd = orig & 7, pos = orig >> 3;
    int wg = (xcd < rr ? xcd * (qq + 1) : rr * (qq + 1) + (xcd - rr) * qq) + pos;
    int bx = wg & 1, by = wg >> 1;
    int row0 = by * 128, col0 = bx * 128;
    int t = threadIdx.x, lane = t & 63, wv = t >> 6;

    int n0 = row0 >> 2, hd0 = col0 >> 6;
    for (int i = t; i < 1024; i += 256) {
        int ln2 = i >> 5, rest = i & 31, hdl = rest >> 4, q16 = rest & 15;
        awS[i] = aw[(long)(n0 + ln2) * 64 + (hd0 + hdl) * 16 + q16];
    }
    __syncthreads();

    int d0 = (wv * 2) * 64 + lane, d1 = d0 + 64;
    int row_0 = d0 >> 2, gp_0 = d0 & 3;
    int row_1 = d1 >> 2, gp_1 = d1 & 3;
    int sw_0 = (gp_0 ^ ((row_0 >> 1) & 3)) << 3;
    int sw_1 = (gp_1 ^ ((row_1 >> 1) & 3)) << 3;
    int m_0 = row0 + row_0, m_1 = row0 + row_1;
    long arow0 = ((long)(m_0 & 3) * NPAD + nodeBase + (m_0 >> 2)) * 256 + sw_0;
    long arow1 = ((long)(m_1 & 3) * NPAD + nodeBase + (m_1 >> 2)) * 256 + sw_1;
    long brow0 = (long)(col0 + row_0) * 256 + sw_0;
    long brow1 = (long)(col0 + row_1) * 256 + sw_1;
    int base0 = wv * 1024, base1 = base0 + 512;

    int wr = wv >> 1, wc = wv & 1, lm = lane & 15, lk = lane >> 4;
    const int gsw = (lk ^ ((lm >> 1) & 3)) * 8;

    f32x4 acc[4][4];
#pragma unroll
    for (int i = 0; i < 4; i++)
#pragma unroll
        for (int j = 0; j < 4; j++) acc[i][j] = (f32x4)(0.f);

#define STAGE_V(db, k0)                                                \
    do {                                                               \
        gl2lds16(AH + arow0 + (k0), &S[(db) * 16384 + base0]);         \
        gl2lds16(AL + arow0 + (k0), &S[(db) * 16384 + 4096 + base0]);  \
        gl2lds16(BH + brow0 + (k0), &S[(db) * 16384 + 8192 + base0]);  \
        gl2lds16(BL + brow0 + (k0), &S[(db) * 16384 + 12288 + base0]); \
        gl2lds16(AH + arow1 + (k0), &S[(db) * 16384 + base1]);         \
        gl2lds16(AL + arow1 + (k0), &S[(db) * 16384 + 4096 + base1]);  \
        gl2lds16(BH + brow1 + (k0), &S[(db) * 16384 + 8192 + base1]);  \
        gl2lds16(BL + brow1 + (k0), &S[(db) * 16384 + 12288 + base1]); \
    } while (0)

    STAGE_V(0, 0);
    for (int ks = 0; ks < 8; ks++) {
        int cur = ks & 1;
        if (ks < 7) {
            STAGE_V(cur ^ 1, (ks + 1) * 32);
            asm volatile("s_waitcnt vmcnt(8)" ::: "memory");
        } else {
            asm volatile("s_waitcnt vmcnt(0)" ::: "memory");
        }
        __builtin_amdgcn_s_barrier();
        asm volatile("" ::: "memory");
        const u16* AhS = S + cur * 16384;
        const u16* AlS = AhS + 4096;
        const u16* BhS = AhS + 8192;
        const u16* BlS = AhS + 12288;
        short8v afh[4], afl[4], bfh[4], bfl[4];
#pragma unroll
        for (int i = 0; i < 4; i++) {
            int am_l = wr * 64 + i * 16 + lm;
            afh[i] = *(const short8v*)&AhS[am_l * 32 + gsw];
            afl[i] = *(const short8v*)&AlS[am_l * 32 + gsw];
            int bc_l = wc * 64 + i * 16 + lm;
            bfh[i] = *(const short8v*)&BhS[bc_l * 32 + gsw];
            bfl[i] = *(const short8v*)&BlS[bc_l * 32 + gsw];
        }
#pragma unroll
        for (int i = 0; i < 4; i++)
#pragma unroll
            for (int j = 0; j < 4; j++) {
                acc[i][j] = __builtin_amdgcn_mfma_f32_16x16x32_bf16(afh[i], bfh[j], acc[i][j], 0, 0, 0);
                acc[i][j] = __builtin_amdgcn_mfma_f32_16x16x32_bf16(afl[i], bfh[j], acc[i][j], 0, 0, 0);
                acc[i][j] = __builtin_amdgcn_mfma_f32_16x16x32_bf16(afh[i], bfl[j], acc[i][j], 0, 0, 0);
            }
        asm volatile("" ::: "memory");
        __builtin_amdgcn_s_barrier();
    }
#undef STAGE_V

    // ---- PV mix + wave-local repack ----
    {
        u16* TH = &S[wv * 8192];
        u16* TL = TH + 4096;
#pragma unroll
        for (int i = 0; i < 4; i++) {
            int rowb = wr * 64 + i * 16 + lk * 4;
            int ln2 = (rowb >> 2);
            const float* ap = &awS[ln2 * 32 + wc * 16];
#pragma unroll
            for (int j = 0; j < 4; j++) {
                int colb = j * 16 + lm;
                float bb = biasV[col0 + wc * 64 + colb];
                float o0 = ap[0] * acc[i][j][0] + ap[1] * acc[i][j][1] + ap[2] * acc[i][j][2] + ap[3] * acc[i][j][3];
                float o1 = ap[4] * acc[i][j][0] + ap[5] * acc[i][j][1] + ap[6] * acc[i][j][2] + ap[7] * acc[i][j][3];
                float o2 = ap[8] * acc[i][j][0] + ap[9] * acc[i][j][1] + ap[10] * acc[i][j][2] + ap[11] * acc[i][j][3];
                float o3 = ap[12] * acc[i][j][0] + ap[13] * acc[i][j][1] + ap[14] * acc[i][j][2] + ap[15] * acc[i][j][3];
                float ov[4] = {o0 + bb, o1 + bb, o2 + bb, o3 + bb};
#pragma unroll
                for (int r = 0; r < 4; r++) {
                    int rowT = i * 16 + lk * 4 + r;
                    int cs = colb ^ ((rowT & 7) << 3);
                    u16 hb = f2bf(ov[r]);
                    TH[rowT * 64 + cs] = hb;
                    TL[rowT * 64 + cs] = f2bf(ov[r] - bf2f(hb));
                }
            }
        }
        __builtin_amdgcn_sched_barrier(0);
#pragma unroll
        for (int it = 0; it < 8; it++) {
            int idx = lane + it * 64;
            int row = idx >> 3, colg = (idx & 7) * 8;
            int lo = row * 64 + (colg ^ ((row & 7) << 3));
            short8v vh = *(const short8v*)&TH[lo];
            short8v vl = *(const short8v*)&TL[lo];
            int mrow = row0 + wr * 64 + row;
            if (mrow < Mc) {
                *(short8v*)&PVH[(long)mrow * 256 + col0 + wc * 64 + colg] = vh;
                *(short8v*)&PVL[(long)mrow * 256 + col0 + wc * 64 + colg] = vl;
            }
        }
    }
}

// ---------------- pipelined 3-term out-proj GEMM ----------------
template <int ACT, int SPLITOUT>
__global__ __launch_bounds__(256) void gemm_out(
    const u16* __restrict__ AH, const u16* __restrict__ AL,
    const u16* __restrict__ BH, const u16* __restrict__ BL,
    const float* __restrict__ b1, const float* __restrict__ b2,
    float* __restrict__ C, u16* __restrict__ H1H,
    int Mc, int Nnodes, int nodeBase, int nwg) {
    __shared__ __attribute__((aligned(16))) u16 S[32768];
    int orig = blockIdx.y * 2 + blockIdx.x;
    int qq = nwg >> 3, rr = nwg & 7;
    int xcd = orig & 7, pos = orig >> 3;
    int wg = (xcd < rr ? xcd * (qq + 1) : rr * (qq + 1) + (xcd - rr) * qq) + pos;
    int bx = wg & 1, by = wg >> 1;
    int row0 = by * 128, col0 = bx * 128;
    int t = threadIdx.x, lane = t & 63, wv = t >> 6;

    int d0 = (wv * 2) * 64 + lane, d1 = d0 + 64;
    int row_0 = d0 >> 2, gp_0 = d0 & 3;
    int row_1 = d1 >> 2, gp_1 = d1 & 3;
    int sw_0 = (gp_0 ^ ((row_0 >> 1) & 3)) << 3;
    int sw_1 = (gp_1 ^ ((row_1 >> 1) & 3)) << 3;
    long arow0 = (long)(row0 + row_0) * 256 + sw_0;
    long arow1 = (long)(row0 + row_1) * 256 + sw_1;
    long brow0 = (long)(col0 + row_0) * 256 + sw_0;
    long brow1 = (long)(col0 + row_1) * 256 + sw_1;
    int base0 = wv * 1024, base1 = base0 + 512;

    int wr = wv >> 1, wc = wv & 1, lm = lane & 15, lk = lane >> 4;
    const int gsw = (lk ^ ((lm >> 1) & 3)) * 8;

    f32x4 acc[4][4];
#pragma unroll
    for (int i = 0; i < 4; i++)
#pragma unroll
        for (int j = 0; j < 4; j++) acc[i][j] = (f32x4)(0.f);

#define STAGE_O(db, k0)                                                \
    do {                                                               \
        gl2lds16(AH + arow0 + (k0), &S[(db) * 16384 + base0]);         \
        gl2lds16(AL + arow0 + (k0), &S[(db) * 16384 + 4096 + base0]);  \
        gl2lds16(BH + brow0 + (k0), &S[(db) * 16384 + 8192 + base0]);  \
        gl2lds16(BL + brow0 + (k0), &S[(db) * 16384 + 12288 + base0]); \
        gl2lds16(AH + arow1 + (k0), &S[(db) * 16384 + base1]);         \
        gl2lds16(AL + arow1 + (k0), &S[(db) * 16384 + 4096 + base1]);  \
        gl2lds16(BH + brow1 + (k0), &S[(db) * 16384 + 8192 + base1]);  \
        gl2lds16(BL + brow1 + (k0), &S[(db) * 16384 + 12288 + base1]); \
    } while (0)

    STAGE_O(0, 0);
    for (int ks = 0; ks < 8; ks++) {
        int cur = ks & 1;
        if (ks < 7) {
            STAGE_O(cur ^ 1, (ks + 1) * 32);
            asm volatile("s_waitcnt vmcnt(8)" ::: "memory");
        } else {
            asm volatile("s_waitcnt vmcnt(0)" ::: "memory");
        }
        __builtin_amdgcn_s_barrier();
        asm volatile("" ::: "memory");
        const u16* AhS = S + cur * 16384;
        const u16* AlS = AhS + 4096;
        const u16* BhS = AhS + 8192;
        const u16* BlS = AhS + 12288;
        short8v afh[4], afl[4], bfh[4], bfl[4];
#pragma unroll
        for (int i = 0; i < 4; i++) {
            int am_l = wr * 64 + i * 16 + lm;
            afh[i] = *(const short8v*)&AhS[am_l * 32 + gsw];
            afl[i] = *(const short8v*)&AlS[am_l * 32 + gsw];
            int bc_l = wc * 64 + i * 16 + lm;
            bfh[i] = *(const short8v*)&BhS[bc_l * 32 + gsw];
            bfl[i] = *(const short8v*)&BlS[bc_l * 32 + gsw];
        }
#pragma unroll
        for (int i = 0; i < 4; i++)
#pragma unroll
            for (int j = 0; j < 4; j++) {
                acc[i][j] = __builtin_amdgcn_mfma_f32_16x16x32_bf16(afh[i], bfh[j], acc[i][j], 0, 0, 0);
                acc[i][j] = __builtin_amdgcn_mfma_f32_16x16x32_bf16(afl[i], bfh[j], acc[i][j], 0, 0, 0);
                acc[i][j] = __builtin_amdgcn_mfma_f32_16x16x32_bf16(afh[i], bfl[j], acc[i][j], 0, 0, 0);
            }
        asm volatile("" ::: "memory");
        __builtin_amdgcn_s_barrier();
    }
#undef STAGE_O

    if (SPLITOUT) {
        u16* T = &S[wv * 4096];
#pragma unroll
        for (int i = 0; i < 4; i++)
#pragma unroll
            for (int j = 0; j < 4; j++) {
                int colb = j * 16 + lm;
                float bb = b1[col0 + wc * 64 + colb] + b2[col0 + wc * 64 + colb];
#pragma unroll
                for (int r = 0; r < 4; r++) {
                    int rowT = i * 16 + lk * 4 + r;
                    float v = acc[i][j][r] + bb;
                    if (ACT == 1) v = v > 0.f ? v : expm1f(v);
                    T[rowT * 64 + (colb ^ ((rowT & 7) << 3))] = f2bf(v);
                }
            }
        __builtin_amdgcn_sched_barrier(0);
#pragma unroll
        for (int it = 0; it < 8; it++) {
            int idx = lane + it * 64;
            int row = idx >> 3, colg = (idx & 7) * 8;
            short8v val = *(const short8v*)&T[row * 64 + (colg ^ ((row & 7) << 3))];
            int mrow = row0 + wr * 64 + row;
            if (mrow < Mc) {
                long cphys = (long)(mrow & 3) * Nnodes + nodeBase + (mrow >> 2);
                *(short8v*)&H1H[cphys * 256 + col0 + wc * 64 + colg] = val;
            }
        }
    } else {
#pragma unroll
        for (int i = 0; i < 4; i++) {
            int rowb = wr * 64 + i * 16 + lk * 4;
#pragma unroll
            for (int j = 0; j < 4; j++) {
                int col = col0 + wc * 64 + j * 16 + lm;
                float bb = b1[col] + b2[col];
#pragma unroll
                for (int r = 0; r < 4; r++) {
                    int m = row0 + rowb + r;
                    if (m >= Mc) continue;
                    long cphys = (long)(m & 3) * Nnodes + nodeBase + (m >> 2);
                    float v = acc[i][j][r] + bb;
                    if (ACT == 1) v = v > 0.f ? v : expm1f(v);
                    C[cphys * 256 + col] = v;
                }
            }
        }
    }
}

// ---------------- attention weights: one wave per node ----------------
__global__ __launch_bounds__(256) void aw_k(const u16* __restrict__ QK, float* __restrict__ aw, int chunkN) {
    int t = threadIdx.x, lane = t & 63, w = t >> 6;
    int node = blockIdx.x * 4 + w;
    if (node >= chunkN) return;
    int vq = lane >> 4, hd = (lane >> 2) & 3, vk = lane & 3;
    const u16* qp = QK + (long)(node * 4 + vq) * 512 + hd * 64;
    const u16* kp = QK + (long)(node * 4 + vk) * 512 + 256 + hd * 64;
    float acc = 0.f;
#pragma unroll
    for (int d0 = 0; d0 < 64; d0 += 8) {
        short8v qv = *(const short8v*)(qp + d0);
        short8v kv = *(const short8v*)(kp + d0);
#pragma unroll
        for (int j = 0; j < 8; j++) acc += bf2f((u16)qv[j]) * bf2f((u16)kv[j]);
    }
    float l = acc * 0.125f;
    float m = l;
    m = fmaxf(m, __shfl_xor(m, 1, 64));
    m = fmaxf(m, __shfl_xor(m, 2, 64));
    float e = expf(l - m);
    float s = e;
    s += __shfl_xor(s, 1, 64);
    s += __shfl_xor(s, 2, 64);
    aw[(long)node * 64 + hd * 16 + vq * 4 + vk] = e / s;
}

// ---------------- launcher ----------------

extern "C" void kernel_launch(void* const* d_in, const int* in_sizes, int n_in,
                              void* d_out, int out_size, void* d_ws, size_t ws_size,
                              hipStream_t stream) {
    const float* x = (const float*)d_in[0];
    const int* ei = (const int*)d_in[1];
    const float* W1 = (const float*)d_in[2];
    const float* att1 = (const float*)d_in[3];
    const float* qkv_w1 = (const float*)d_in[4];
    const float* qkv_b1 = (const float*)d_in[5];
    const float* out_w1 = (const float*)d_in[6];
    const float* out_b1 = (const float*)d_in[7];
    const float* bias1 = (const float*)d_in[8];
    const float* W2 = (const float*)d_in[9];
    const float* att2 = (const float*)d_in[10];
    const float* qkv_w2 = (const float*)d_in[11];
    const float* qkv_b2 = (const float*)d_in[12];
    const float* out_w2 = (const float*)d_in[13];
    const float* out_b2 = (const float*)d_in[14];
    const float* bias2 = (const float*)d_in[15];
    float* out = (float*)d_out;

    const int Nn = NN, E = EE, Etot = ETOT;
    const int MROWS = 40064;

    char* wsB = (char*)d_ws;
    size_t off = 0;
    auto alloc = [&](size_t bytes) -> void* {
        void* p = wsB + off;
        off += (bytes + 255) & ~(size_t)255;
        return p;
    };
    u16* W1TH = (u16*)alloc((size_t)256 * 64 * 2);
    u16* W1TL = (u16*)alloc((size_t)256 * 64 * 2);
    u16* W2TH = (u16*)alloc((size_t)256 * 256 * 2);
    u16* W2TL = (u16*)alloc((size_t)256 * 256 * 2);
    u16* qw1H = (u16*)alloc((size_t)768 * 256 * 2);
    u16* qw1L = (u16*)alloc((size_t)768 * 256 * 2);
    u16* qw2H = (u16*)alloc((size_t)768 * 256 * 2);
    u16* qw2L = (u16*)alloc((size_t)768 * 256 * 2);
    u16* ow1H = (u16*)alloc((size_t)256 * 256 * 2);
    u16* ow1L = (u16*)alloc((size_t)256 * 256 * 2);
    u16* ow2H = (u16*)alloc((size_t)256 * 256 * 2);
    u16* ow2L = (u16*)alloc((size_t)256 * 256 * 2);
    u16* xH = (u16*)alloc((size_t)MROWS * 64 * 2);
    u16* h1H = (u16*)alloc((size_t)MROWS * 256 * 2);
    u16* hbufB = (u16*)alloc((size_t)Nn * 4 * DD * 2);
    u16* aggH = (u16*)alloc((size_t)4 * NPAD * DD * 2);
    u16* aggL = (u16*)alloc((size_t)4 * NPAD * DD * 2);
    float* asrc = (float*)alloc((size_t)Nn * 4 * 4);
    float* adst = (float*)alloc((size_t)Nn * 4 * 4);
    float* wts = (float*)alloc((size_t)Etot * 4 * 4);
    float* hsum = (float*)alloc(4 * 4);
    float* pmax = (float*)alloc((size_t)256 * 4 * 4);
    int* deg = (int*)alloc((size_t)Nn * 4);
    int* offs = (int*)alloc((size_t)Nn * 4);
    int* cursor = (int*)alloc((size_t)Nn * 4);
    int* csr_eid = (int*)alloc((size_t)Etot * 4);
    int* csr_src = (int*)alloc((size_t)Etot * 4);

    auto aligned = [](size_t b) { return (b + 255) & ~(size_t)255; };
    auto mpad_of = [](int cN) { return ((cN * 4 + 127) / 128) * 128; };
    int nchunks = 40;
    {
        const int cands[8] = {1, 2, 4, 5, 8, 10, 20, 40};
        for (int ci = 0; ci < 8; ci++) {
            int cN = Nn / cands[ci];
            long mp = mpad_of(cN);
            size_t need = off + aligned((size_t)mp * 512 * 2) + 2 * aligned((size_t)mp * 256 * 2) +
                          aligned((size_t)(mp / 4) * 64 * 4);
            if (need <= ws_size) { nchunks = cands[ci]; break; }
        }
    }
    int chunkN = Nn / nchunks;
    int Mpad = mpad_of(chunkN);
    u16* QKb = (u16*)alloc((size_t)Mpad * 512 * 2);
    u16* PVH = (u16*)alloc((size_t)Mpad * 256 * 2);
    u16* PVL = (u16*)alloc((size_t)Mpad * 256 * 2);
    float* awb = (float*)alloc((size_t)(Mpad / 4) * 64 * 4);

    // --- prep ---
    transpose_split_k<<<(64 * 256 + 255) / 256, 256, 0, stream>>>(W1, W1TH, W1TL, 64, 256);
    transpose_split_k<<<(256 * 256 + 255) / 256, 256, 0, stream>>>(W2, W2TH, W2TL, 256, 256);
    split_k<<<(768 * 256 + 255) / 256, 256, 0, stream>>>(qkv_w1, qw1H, qw1L, 768 * 256);
    split_k<<<(768 * 256 + 255) / 256, 256, 0, stream>>>(qkv_w2, qw2H, qw2L, 768 * 256);
    split_k<<<(256 * 256 + 255) / 256, 256, 0, stream>>>(out_w1, ow1H, ow1L, 256 * 256);
    split_k<<<(256 * 256 + 255) / 256, 256, 0, stream>>>(out_w2, ow2H, ow2L, 256 * 256);
    cvt_k<<<(40000 * 64 + 255) / 256, 256, 0, stream>>>(x, xH, 40000 * 64);
    hipMemsetAsync(deg, 0, Nn * sizeof(int), stream);
    deg_k<<<(Etot + 255) / 256, 256, 0, stream>>>(ei, deg, E, Etot);
    scan_k<<<1, 1024, 0, stream>>>(deg, offs, cursor, Nn);
    csr_fill_k<<<(Etot + 255) / 256, 256, 0, stream>>>(ei, cursor, csr_eid, csr_src, E, Etot);

    auto scoresAndAgg = [&]() {
        edge_scores_max_k<<<256, 256, 0, stream>>>(ei, asrc, adst, wts, pmax, E, Etot);
        hipMemsetAsync(hsum, 0, 16, stream);
        exp_sum_k<<<(Etot * 4 + 255) / 256, 256, 0, stream>>>(wts, pmax, hsum, Etot * 4);
        agg4_k<<<dim3((Nn + 3) / 4, 4), 256, 0, stream>>>(hbufB, wts, offs, deg, csr_eid, csr_src,
                                                          hsum, aggH, aggL, Nn);
    };

    int gy = Mpad / 128;

    // ---------------- layer 1 ----------------
    hipMemsetAsync(asrc, 0, (size_t)Nn * 4 * 4 * 2, stream);
    gemm_h<64><<<dim3(2, 313), 256, 0, stream>>>(xH, W1TH, hbufB, 40000, Nn, att1, asrc, adst, 626);
    scoresAndAgg();
    for (int c = 0; c < nchunks; c++) {
        int nb = c * chunkN;
        int Mc = chunkN * 4;
        gemm_qk<<<dim3(4, gy), 256, 0, stream>>>(aggH, qw1H, qkv_b1, QKb, Mc, nb, 4 * gy);
        aw_k<<<(chunkN + 3) / 4, 256, 0, stream>>>(QKb, awb, chunkN);
        gemm_vpv<<<dim3(2, gy), 256, 0, stream>>>(aggH, aggL, qw1H + 512 * 256, qw1L + 512 * 256,
                                                  qkv_b1 + 512, awb, PVH, PVL, Mc, nb, 2 * gy);
        gemm_out<1, 1><<<dim3(2, gy), 256, 0, stream>>>(PVH, PVL, ow1H, ow1L, out_b1, bias1,
                                                        nullptr, h1H, Mc, Nn, nb, 2 * gy);
    }

    // ---------------- layer 2 ----------------
    hipMemsetAsync(asrc, 0, (size_t)Nn * 4 * 4 * 2, stream);
    gemm_h<256><<<dim3(2, 313), 256, 0, stream>>>(h1H, W2TH, hbufB, 40000, Nn, att2, asrc, adst, 626);
    scoresAndAgg();
    for (int c = 0; c < nchunks; c++) {
        int nb = c * chunkN;
        int Mc = chunkN * 4;
        gemm_qk<<<dim3(4, gy), 256, 0, stream>>>(aggH, qw2H, qkv_b2, QKb, Mc, nb, 4 * gy);
        aw_k<<<(chunkN + 3) / 4, 256, 0, stream>>>(QKb, awb, chunkN);
        gemm_vpv<<<dim3(2, gy), 256, 0, stream>>>(aggH, aggL, qw2H + 512 * 256, qw2L + 512 * 256,
                                                  qkv_b2 + 512, awb, PVH, PVL, Mc, nb, 2 * gy);
        gemm_out<0, 0><<<dim3(2, gy), 256, 0, stream>>>(PVH, PVL, ow2H, ow2L, out_b2, bias2,
                                                        out, nullptr, Mc, Nn, nb, 2 * gy);
    }
}

// Round 12
// 491.572 us; speedup vs baseline: 1.0229x; 1.0229x over previous
//
#include <hip/hip_runtime.h>

#define NN 10000
#define NPAD 10048
#define EE 128000
#define ETOT 138000
#define DD 256
#define DIN 64

typedef unsigned short u16;
typedef __attribute__((ext_vector_type(8))) short short8v;
typedef __attribute__((ext_vector_type(4))) short short4v;
typedef __attribute__((ext_vector_type(4))) float f32x4;

__device__ __forceinline__ u16 f2bf(float f) {
    union { float f; unsigned u; } a; a.f = f;
    unsigned r = a.u + 0x7fffu + ((a.u >> 16) & 1u);
    return (u16)(r >> 16);
}
__device__ __forceinline__ float bf2f(u16 b) {
    union { unsigned u; float f; } a; a.u = ((unsigned)b) << 16;
    return a.f;
}

__device__ __forceinline__ void gl2lds16(const void* g, void* l) {
    __builtin_amdgcn_global_load_lds((const __attribute__((address_space(1))) unsigned int*)g,
                                     (__attribute__((address_space(3))) unsigned int*)l, 16, 0, 0);
}

// ---------------- weight/input split kernels ----------------

__global__ void split_k(const float* __restrict__ W, u16* __restrict__ H, u16* __restrict__ L, int total) {
    int i = blockIdx.x * 256 + threadIdx.x;
    if (i >= total) return;
    float f = W[i];
    u16 h = f2bf(f);
    H[i] = h;
    L[i] = f2bf(f - bf2f(h));
}

__global__ void cvt_k(const float* __restrict__ W, u16* __restrict__ H, int total) {
    int i = blockIdx.x * 256 + threadIdx.x;
    if (i >= total) return;
    H[i] = f2bf(W[i]);
}

__global__ void transpose_split_k(const float* __restrict__ W, u16* __restrict__ H, u16* __restrict__ L,
                                  int R, int C) {
    int idx = blockIdx.x * 256 + threadIdx.x;
    if (idx >= R * C) return;
    int r = idx / C, c = idx % C;
    float f = W[idx];
    u16 h = f2bf(f);
    H[c * R + r] = h;
    L[c * R + r] = f2bf(f - bf2f(h));
}

// ---------------- CSR build ----------------

__global__ void deg_k(const int* __restrict__ ei, int* __restrict__ deg, int E, int Etot) {
    int e = blockIdx.x * 256 + threadIdx.x;
    if (e >= Etot) return;
    int dn = (e < E) ? ei[E + e] : (e - E);
    atomicAdd(&deg[dn], 1);
}

__global__ __launch_bounds__(1024) void scan_k(const int* __restrict__ deg, int* __restrict__ offs,
                                               int* __restrict__ cursor, int Nn) {
    __shared__ int ps[1024];
    int t = threadIdx.x;
    int chunk = (Nn + 1023) >> 10;
    int i0 = t * chunk;
    int local = 0;
    for (int i = 0; i < chunk; i++) {
        int idx = i0 + i;
        if (idx < Nn) local += deg[idx];
    }
    ps[t] = local;
    __syncthreads();
    for (int off = 1; off < 1024; off <<= 1) {
        int v = 0;
        if (t >= off) v = ps[t - off];
        __syncthreads();
        if (t >= off) ps[t] += v;
        __syncthreads();
    }
    int run = ps[t] - local;
    for (int i = 0; i < chunk; i++) {
        int idx = i0 + i;
        if (idx < Nn) {
            offs[idx] = run;
            cursor[idx] = run;
            run += deg[idx];
        }
    }
}

__global__ void csr_fill_k(const int* __restrict__ ei, int* __restrict__ cursor,
                           int* __restrict__ csr_eid, int* __restrict__ csr_src, int E, int Etot) {
    int e = blockIdx.x * 256 + threadIdx.x;
    if (e >= Etot) return;
    int s, dn;
    if (e < E) { s = ei[e]; dn = ei[E + e]; }
    else { s = dn = e - E; }
    int pos = atomicAdd(&cursor[dn], 1);
    csr_eid[pos] = e;
    csr_src[pos] = s;
}

// ---------------- GAT score path ----------------

__global__ __launch_bounds__(256) void edge_scores_max_k(
    const int* __restrict__ ei, const float* __restrict__ asrc, const float* __restrict__ adst,
    float* __restrict__ sc, float* __restrict__ pmax, int E, int Etot) {
    int t = threadIdx.x;
    int total = Etot * 4;
    int gid = blockIdx.x * 256 + t;
    int stride = gridDim.x * 256;
    float m = -3.4e38f;
    for (int idx = gid; idx < total; idx += stride) {
        int e = idx >> 2, hd = idx & 3;
        int s, dn;
        if (e < E) { s = ei[e]; dn = ei[E + e]; }
        else { s = dn = e - E; }
        float v = asrc[s * 4 + hd] + adst[dn * 4 + hd];
        sc[idx] = v;
        m = fmaxf(m, v);
    }
    __shared__ float lds[256];
    lds[t] = m;
    __syncthreads();
    if (t < 4) {
        float r = -3.4e38f;
        for (int j = t; j < 256; j += 4) r = fmaxf(r, lds[j]);
        pmax[blockIdx.x * 4 + t] = r;
    }
}

__global__ __launch_bounds__(256) void exp_sum_k(float* __restrict__ sc, const float* __restrict__ pmax,
                                                 float* __restrict__ hsum, int total) {
    __shared__ float red[256];
    __shared__ float hm[4];
    __shared__ float ls[4];
    int t = threadIdx.x;
    float m = -3.4e38f;
    for (int j = t; j < 1024; j += 256) m = fmaxf(m, pmax[j]);
    red[t] = m;
    if (t < 4) ls[t] = 0.f;
    __syncthreads();
    if (t < 4) {
        float r = -3.4e38f;
        for (int j = t; j < 256; j += 4) r = fmaxf(r, red[j]);
        hm[t] = r;
    }
    __syncthreads();
    int idx = blockIdx.x * 256 + t;
    if (idx < total) {
        int hd = idx & 3;
        float w = expf(sc[idx] - hm[hd]);
        sc[idx] = w;
        atomicAdd(&ls[hd], w);
    }
    __syncthreads();
    if (t < 4) atomicAdd(&hsum[t], ls[t]);
}

// ---------------- vectorized gather aggregation (wsort fused, unroll-4) ----------------
// thread -> (view v = t>>6, feature group g = t&63 covering feats 4g..4g+3)
__global__ __launch_bounds__(256) void agg3_k(const u16* __restrict__ hB, const float* __restrict__ wts,
                                              const int* __restrict__ offs, const int* __restrict__ deg,
                                              const int* __restrict__ csr_eid, const int* __restrict__ csr_src,
                                              const float* __restrict__ hsum,
                                              u16* __restrict__ aggH, u16* __restrict__ aggL, int Nn) {
    int n = blockIdx.x, t = threadIdx.x;
    int v = t >> 6, g = t & 63;
    int hd = g >> 4;
    float inv = 1.0f / hsum[hd];
    int o0 = offs[n], dg = deg[n];
    float a0 = 0.f, a1 = 0.f, a2 = 0.f, a3 = 0.f;
    const long vb = (long)v * 256 + g * 4;
    int p = 0;
    for (; p + 3 < dg; p += 4) {
        int e0 = csr_eid[o0 + p], e1 = csr_eid[o0 + p + 1];
        int e2 = csr_eid[o0 + p + 2], e3 = csr_eid[o0 + p + 3];
        int s0 = csr_src[o0 + p], s1 = csr_src[o0 + p + 1];
        int s2 = csr_src[o0 + p + 2], s3 = csr_src[o0 + p + 3];
        short4v h0 = *(const short4v*)&hB[(long)s0 * 1024 + vb];
        short4v h1 = *(const short4v*)&hB[(long)s1 * 1024 + vb];
        short4v h2 = *(const short4v*)&hB[(long)s2 * 1024 + vb];
        short4v h3 = *(const short4v*)&hB[(long)s3 * 1024 + vb];
        float w0 = wts[e0 * 4 + hd] * inv;
        float w1 = wts[e1 * 4 + hd] * inv;
        float w2 = wts[e2 * 4 + hd] * inv;
        float w3 = wts[e3 * 4 + hd] * inv;
        a0 += w0 * bf2f((u16)h0[0]) + w1 * bf2f((u16)h1[0]) + w2 * bf2f((u16)h2[0]) + w3 * bf2f((u16)h3[0]);
        a1 += w0 * bf2f((u16)h0[1]) + w1 * bf2f((u16)h1[1]) + w2 * bf2f((u16)h2[1]) + w3 * bf2f((u16)h3[1]);
        a2 += w0 * bf2f((u16)h0[2]) + w1 * bf2f((u16)h1[2]) + w2 * bf2f((u16)h2[2]) + w3 * bf2f((u16)h3[2]);
        a3 += w0 * bf2f((u16)h0[3]) + w1 * bf2f((u16)h1[3]) + w2 * bf2f((u16)h2[3]) + w3 * bf2f((u16)h3[3]);
    }
    for (; p < dg; p++) {
        int e0 = csr_eid[o0 + p];
        int s0 = csr_src[o0 + p];
        float w0 = wts[e0 * 4 + hd] * inv;
        short4v h0 = *(const short4v*)&hB[(long)s0 * 1024 + vb];
        a0 += w0 * bf2f((u16)h0[0]);
        a1 += w0 * bf2f((u16)h0[1]);
        a2 += w0 * bf2f((u16)h0[2]);
        a3 += w0 * bf2f((u16)h0[3]);
    }
    union { short4v v4; u16 u[4]; } oh, ol;
    float av[4] = {a0, a1, a2, a3};
#pragma unroll
    for (int c = 0; c < 4; c++) {
        u16 hb = f2bf(av[c]);
        oh.u[c] = hb;
        ol.u[c] = f2bf(av[c] - bf2f(hb));
    }
    long ob = ((long)v * NPAD + n) * 256 + g * 4;
    *(short4v*)&aggH[ob] = oh.v4;
    *(short4v*)&aggL[ob] = ol.v4;
}

// ---------------- pipelined 1-term bf16 h-GEMM, wave-local repack + fused att-scores ----------------
template <int KK>
__global__ __launch_bounds__(256) void gemm_h(
    const u16* __restrict__ AH, const u16* __restrict__ BH,
    u16* __restrict__ CH, int M, int Nnodes,
    const float* __restrict__ attw, float* __restrict__ asrc, float* __restrict__ adst, int nwg) {
    __shared__ __attribute__((aligned(16))) u16 S[16384];  // 32 KB flat
    int orig = blockIdx.y * 2 + blockIdx.x;
    int qq = nwg >> 3, rr = nwg & 7;
    int xcd = orig & 7, pos = orig >> 3;
    int wg = (xcd < rr ? xcd * (qq + 1) : rr * (qq + 1) + (xcd - rr) * qq) + pos;
    int bx = wg & 1, by = wg >> 1;
    int row0 = by * 128, col0 = bx * 128;
    int t = threadIdx.x, lane = t & 63, wv = t >> 6;

    int d0 = (wv * 2) * 64 + lane, d1 = d0 + 64;
    int row_0 = d0 >> 2, gp_0 = d0 & 3;
    int row_1 = d1 >> 2, gp_1 = d1 & 3;
    int sw_0 = (gp_0 ^ ((row_0 >> 1) & 3)) << 3;
    int sw_1 = (gp_1 ^ ((row_1 >> 1) & 3)) << 3;
    long arow0 = (long)(row0 + row_0) * KK + sw_0;
    long arow1 = (long)(row0 + row_1) * KK + sw_1;
    long brow0 = (long)(col0 + row_0) * KK + sw_0;
    long brow1 = (long)(col0 + row_1) * KK + sw_1;
    int base0 = wv * 1024, base1 = base0 + 512;

    int wr = wv >> 1, wc = wv & 1, lm = lane & 15, lk = lane >> 4;
    const int gsw = (lk ^ ((lm >> 1) & 3)) * 8;

    f32x4 acc[4][4];
#pragma unroll
    for (int i = 0; i < 4; i++)
#pragma unroll
        for (int j = 0; j < 4; j++) acc[i][j] = (f32x4)(0.f);

#define STAGE_H(db, k0)                                               \
    do {                                                              \
        gl2lds16(AH + arow0 + (k0), &S[(db) * 8192 + base0]);         \
        gl2lds16(BH + brow0 + (k0), &S[(db) * 8192 + 4096 + base0]);  \
        gl2lds16(AH + arow1 + (k0), &S[(db) * 8192 + base1]);         \
        gl2lds16(BH + brow1 + (k0), &S[(db) * 8192 + 4096 + base1]);  \
    } while (0)

    STAGE_H(0, 0);
#pragma unroll
    for (int ks = 0; ks < KK / 32; ks++) {
        int cur = ks & 1;
        if (ks < KK / 32 - 1) {
            STAGE_H(cur ^ 1, (ks + 1) * 32);
            asm volatile("s_waitcnt vmcnt(4)" ::: "memory");
        } else {
            asm volatile("s_waitcnt vmcnt(0)" ::: "memory");
        }
        __builtin_amdgcn_s_barrier();
        asm volatile("" ::: "memory");
        const u16* AhS = S + cur * 8192;
        const u16* BhS = S + cur * 8192 + 4096;
        short8v af[4], bf[4];
#pragma unroll
        for (int i = 0; i < 4; i++) {
            af[i] = *(const short8v*)&AhS[(wr * 64 + i * 16 + lm) * 32 + gsw];
            bf[i] = *(const short8v*)&BhS[(wc * 64 + i * 16 + lm) * 32 + gsw];
        }
#pragma unroll
        for (int i = 0; i < 4; i++)
#pragma unroll
            for (int j = 0; j < 4; j++)
                acc[i][j] = __builtin_amdgcn_mfma_f32_16x16x32_bf16(af[i], bf[j], acc[i][j], 0, 0, 0);
        asm volatile("" ::: "memory");
        __builtin_amdgcn_s_barrier();
    }
#undef STAGE_H

    // ---- wave-local repack epilogue ----
    {
        u16* T = &S[wv * 4096];
#pragma unroll
        for (int i = 0; i < 4; i++)
#pragma unroll
            for (int j = 0; j < 4; j++) {
                int colb = j * 16 + lm;
#pragma unroll
                for (int r = 0; r < 4; r++) {
                    int rowT = i * 16 + lk * 4 + r;
                    T[rowT * 64 + (colb ^ ((rowT & 7) << 3))] = f2bf(acc[i][j][r]);
                }
            }
        __builtin_amdgcn_sched_barrier(0);
#pragma unroll
        for (int it = 0; it < 8; it++) {
            int idx = lane + it * 64;
            int row = idx >> 3, colg = (idx & 7) * 8;
            short8v val = *(const short8v*)&T[row * 64 + (colg ^ ((row & 7) << 3))];
            int mrow = row0 + wr * 64 + row;
            if (mrow < M) {
                int vv = mrow / Nnodes;
                int n = mrow - vv * Nnodes;
                *(short8v*)&CH[((long)n * 4 + vv) * 256 + col0 + wc * 64 + colg] = val;
            }
        }
    }

    // fused GAT attention scores (register-only)
    {
        int hd = (col0 >> 6) + wc;
        const float* attS = attw + hd * 128;
        const float* attD = attS + 64;
#pragma unroll
        for (int i = 0; i < 4; i++) {
            int rowb = row0 + wr * 64 + i * 16 + lk * 4;
#pragma unroll
            for (int r = 0; r < 4; r++) {
                int mrow = rowb + r;
                float sS = 0.f, sD = 0.f;
#pragma unroll
                for (int j = 0; j < 4; j++) {
                    float hv2 = acc[i][j][r];
                    float hl = hv2 > 0.f ? hv2 : 0.2f * hv2;
                    int f = j * 16 + lm;
                    sS += hl * attS[f];
                    sD += hl * attD[f];
                }
#pragma unroll
                for (int msk = 1; msk < 16; msk <<= 1) {
                    sS += __shfl_xor(sS, msk, 64);
                    sD += __shfl_xor(sD, msk, 64);
                }
                if (lm == 0 && mrow < M) {
                    int vv = mrow / Nnodes;
                    int n = mrow - vv * Nnodes;
                    atomicAdd(&asrc[n * 4 + hd], 0.25f * sS);
                    atomicAdd(&adst[n * 4 + hd], 0.25f * sD);
                }
            }
        }
    }
}

// ---------------- pipelined single-bf16 QK GEMM, wave-local repack ----------------
__global__ __launch_bounds__(256) void gemm_qk(
    const u16* __restrict__ AH, const u16* __restrict__ BH,
    const float* __restrict__ bias, u16* __restrict__ QK,
    int Mc, int nodeBase, int nwg) {
    __shared__ __attribute__((aligned(16))) u16 S[16384];
    int orig = blockIdx.y * 4 + blockIdx.x;
    int qq = nwg >> 3, rr = nwg & 7;
    int xcd = orig & 7, pos = orig >> 3;
    int wg = (xcd < rr ? xcd * (qq + 1) : rr * (qq + 1) + (xcd - rr) * qq) + pos;
    int bx = wg & 3, by = wg >> 2;
    int row0 = by * 128, col0 = bx * 128;
    int t = threadIdx.x, lane = t & 63, wv = t >> 6;

    int d0 = (wv * 2) * 64 + lane, d1 = d0 + 64;
    int row_0 = d0 >> 2, gp_0 = d0 & 3;
    int row_1 = d1 >> 2, gp_1 = d1 & 3;
    int sw_0 = (gp_0 ^ ((row_0 >> 1) & 3)) << 3;
    int sw_1 = (gp_1 ^ ((row_1 >> 1) & 3)) << 3;
    int m_0 = row0 + row_0, m_1 = row0 + row_1;
    long arow0 = ((long)(m_0 & 3) * NPAD + nodeBase + (m_0 >> 2)) * 256 + sw_0;
    long arow1 = ((long)(m_1 & 3) * NPAD + nodeBase + (m_1 >> 2)) * 256 + sw_1;
    long brow0 = (long)(col0 + row_0) * 256 + sw_0;
    long brow1 = (long)(col0 + row_1) * 256 + sw_1;
    int base0 = wv * 1024, base1 = base0 + 512;

    int wr = wv >> 1, wc = wv & 1, lm = lane & 15, lk = lane >> 4;
    const int gsw = (lk ^ ((lm >> 1) & 3)) * 8;

    f32x4 acc[4][4];
#pragma unroll
    for (int i = 0; i < 4; i++)
#pragma unroll
        for (int j = 0; j < 4; j++) acc[i][j] = (f32x4)(0.f);

#define STAGE_QK(db, k0)                                              \
    do {                                                              \
        gl2lds16(AH + arow0 + (k0), &S[(db) * 8192 + base0]);         \
        gl2lds16(BH + brow0 + (k0), &S[(db) * 8192 + 4096 + base0]);  \
        gl2lds16(AH + arow1 + (k0), &S[(db) * 8192 + base1]);         \
        gl2lds16(BH + brow1 + (k0), &S[(db) * 8192 + 4096 + base1]);  \
    } while (0)

    STAGE_QK(0, 0);
    for (int ks = 0; ks < 8; ks++) {
        int cur = ks & 1;
        if (ks < 7) {
            STAGE_QK(cur ^ 1, (ks + 1) * 32);
            asm volatile("s_waitcnt vmcnt(4)" ::: "memory");
        } else {
            asm volatile("s_waitcnt vmcnt(0)" ::: "memory");
        }
        __builtin_amdgcn_s_barrier();
        asm volatile("" ::: "memory");
        const u16* AhS = S + cur * 8192;
        const u16* BhS = S + cur * 8192 + 4096;
        short8v af[4], bf[4];
#pragma unroll
        for (int i = 0; i < 4; i++) {
            af[i] = *(const short8v*)&AhS[(wr * 64 + i * 16 + lm) * 32 + gsw];
            bf[i] = *(const short8v*)&BhS[(wc * 64 + i * 16 + lm) * 32 + gsw];
        }
#pragma unroll
        for (int i = 0; i < 4; i++)
#pragma unroll
            for (int j = 0; j < 4; j++)
                acc[i][j] = __builtin_amdgcn_mfma_f32_16x16x32_bf16(af[i], bf[j], acc[i][j], 0, 0, 0);
        asm volatile("" ::: "memory");
        __builtin_amdgcn_s_barrier();
    }
#undef STAGE_QK

    // ---- wave-local repack epilogue ----
    {
        u16* T = &S[wv * 4096];
#pragma unroll
        for (int i = 0; i < 4; i++)
#pragma unroll
            for (int j = 0; j < 4; j++) {
                int colb = j * 16 + lm;
                float bb = bias[col0 + wc * 64 + colb];
#pragma unroll
                for (int r = 0; r < 4; r++) {
                    int rowT = i * 16 + lk * 4 + r;
                    T[rowT * 64 + (colb ^ ((rowT & 7) << 3))] = f2bf(acc[i][j][r] + bb);
                }
            }
        __builtin_amdgcn_sched_barrier(0);
#pragma unroll
        for (int it = 0; it < 8; it++) {
            int idx = lane + it * 64;
            int row = idx >> 3, colg = (idx & 7) * 8;
            short8v val = *(const short8v*)&T[row * 64 + (colg ^ ((row & 7) << 3))];
            int mrow = row0 + wr * 64 + row;
            if (mrow < Mc) *(short8v*)&QK[(long)mrow * 512 + col0 + wc * 64 + colg] = val;
        }
    }
}

// ---------------- pipelined 3-term V GEMM with fused PV + wave-local repack ----------------
__global__ __launch_bounds__(256) void gemm_vpv(
    const u16* __restrict__ AH, const u16* __restrict__ AL,
    const u16* __restrict__ BH, const u16* __restrict__ BL,
    const float* __restrict__ biasV, const float* __restrict__ aw,
    u16* __restrict__ PVH, u16* __restrict__ PVL,
    int Mc, int nodeBase, int nwg) {
    __shared__ __attribute__((aligned(16))) u16 S[32768];  // 64 KB flat
    __shared__ float awS[1024];
    int orig = blockIdx.y * 2 + blockIdx.x;
    int qq = nwg >> 3, rr = nwg & 7;
    int xcd = orig & 7, pos = orig >> 3;
    int wg = (xcd < rr ? xcd * (qq + 1) : rr * (qq + 1) + (xcd - rr) * qq) + pos;
    int bx = wg & 1, by = wg >> 1;
    int row0 = by * 128, col0 = bx * 128;
    int t = threadIdx.x, lane = t & 63, wv = t >> 6;

    int n0 = row0 >> 2, hd0 = col0 >> 6;
    for (int i = t; i < 1024; i += 256) {
        int ln2 = i >> 5, rest = i & 31, hdl = rest >> 4, q16 = rest & 15;
        awS[i] = aw[(long)(n0 + ln2) * 64 + (hd0 + hdl) * 16 + q16];
    }
    __syncthreads();

    int d0 = (wv * 2) * 64 + lane, d1 = d0 + 64;
    int row_0 = d0 >> 2, gp_0 = d0 & 3;
    int row_1 = d1 >> 2, gp_1 = d1 & 3;
    int sw_0 = (gp_0 ^ ((row_0 >> 1) & 3)) << 3;
    int sw_1 = (gp_1 ^ ((row_1 >> 1) & 3)) << 3;
    int m_0 = row0 + row_0, m_1 = row0 + row_1;
    long arow0 = ((long)(m_0 & 3) * NPAD + nodeBase + (m_0 >> 2)) * 256 + sw_0;
    long arow1 = ((long)(m_1 & 3) * NPAD + nodeBase + (m_1 >> 2)) * 256 + sw_1;
    long brow0 = (long)(col0 + row_0) * 256 + sw_0;
    long brow1 = (long)(col0 + row_1) * 256 + sw_1;
    int base0 = wv * 1024, base1 = base0 + 512;

    int wr = wv >> 1, wc = wv & 1, lm = lane & 15, lk = lane >> 4;
    const int gsw = (lk ^ ((lm >> 1) & 3)) * 8;

    f32x4 acc[4][4];
#pragma unroll
    for (int i = 0; i < 4; i++)
#pragma unroll
        for (int j = 0; j < 4; j++) acc[i][j] = (f32x4)(0.f);

#define STAGE_V(db, k0)                                                \
    do {                                                               \
        gl2lds16(AH + arow0 + (k0), &S[(db) * 16384 + base0]);         \
        gl2lds16(AL + arow0 + (k0), &S[(db) * 16384 + 4096 + base0]);  \
        gl2lds16(BH + brow0 + (k0), &S[(db) * 16384 + 8192 + base0]);  \
        gl2lds16(BL + brow0 + (k0), &S[(db) * 16384 + 12288 + base0]); \
        gl2lds16(AH + arow1 + (k0), &S[(db) * 16384 + base1]);         \
        gl2lds16(AL + arow1 + (k0), &S[(db) * 16384 + 4096 + base1]);  \
        gl2lds16(BH + brow1 + (k0), &S[(db) * 16384 + 8192 + base1]);  \
        gl2lds16(BL + brow1 + (k0), &S[(db) * 16384 + 12288 + base1]); \
    } while (0)

    STAGE_V(0, 0);
    for (int ks = 0; ks < 8; ks++) {
        int cur = ks & 1;
        if (ks < 7) {
            STAGE_V(cur ^ 1, (ks + 1) * 32);
            asm volatile("s_waitcnt vmcnt(8)" ::: "memory");
        } else {
            asm volatile("s_waitcnt vmcnt(0)" ::: "memory");
        }
        __builtin_amdgcn_s_barrier();
        asm volatile("" ::: "memory");
        const u16* AhS = S + cur * 16384;
        const u16* AlS = AhS + 4096;
        const u16* BhS = AhS + 8192;
        const u16* BlS = AhS + 12288;
        short8v afh[4], afl[4], bfh[4], bfl[4];
#pragma unroll
        for (int i = 0; i < 4; i++) {
            int am_l = wr * 64 + i * 16 + lm;
            afh[i] = *(const short8v*)&AhS[am_l * 32 + gsw];
            afl[i] = *(const short8v*)&AlS[am_l * 32 + gsw];
            int bc_l = wc * 64 + i * 16 + lm;
            bfh[i] = *(const short8v*)&BhS[bc_l * 32 + gsw];
            bfl[i] = *(const short8v*)&BlS[bc_l * 32 + gsw];
        }
#pragma unroll
        for (int i = 0; i < 4; i++)
#pragma unroll
            for (int j = 0; j < 4; j++) {
                acc[i][j] = __builtin_amdgcn_mfma_f32_16x16x32_bf16(afh[i], bfh[j], acc[i][j], 0, 0, 0);
                acc[i][j] = __builtin_amdgcn_mfma_f32_16x16x32_bf16(afl[i], bfh[j], acc[i][j], 0, 0, 0);
                acc[i][j] = __builtin_amdgcn_mfma_f32_16x16x32_bf16(afh[i], bfl[j], acc[i][j], 0, 0, 0);
            }
        asm volatile("" ::: "memory");
        __builtin_amdgcn_s_barrier();
    }
#undef STAGE_V

    // ---- PV mix + wave-local repack ----
    {
        u16* TH = &S[wv * 8192];
        u16* TL = TH + 4096;
#pragma unroll
        for (int i = 0; i < 4; i++) {
            int rowb = wr * 64 + i * 16 + lk * 4;
            int ln2 = (rowb >> 2);
            const float* ap = &awS[ln2 * 32 + wc * 16];
#pragma unroll
            for (int j = 0; j < 4; j++) {
                int colb = j * 16 + lm;
                float bb = biasV[col0 + wc * 64 + colb];
                float o0 = ap[0] * acc[i][j][0] + ap[1] * acc[i][j][1] + ap[2] * acc[i][j][2] + ap[3] * acc[i][j][3];
                float o1 = ap[4] * acc[i][j][0] + ap[5] * acc[i][j][1] + ap[6] * acc[i][j][2] + ap[7] * acc[i][j][3];
                float o2 = ap[8] * acc[i][j][0] + ap[9] * acc[i][j][1] + ap[10] * acc[i][j][2] + ap[11] * acc[i][j][3];
                float o3 = ap[12] * acc[i][j][0] + ap[13] * acc[i][j][1] + ap[14] * acc[i][j][2] + ap[15] * acc[i][j][3];
                float ov[4] = {o0 + bb, o1 + bb, o2 + bb, o3 + bb};
#pragma unroll
                for (int r = 0; r < 4; r++) {
                    int rowT = i * 16 + lk * 4 + r;
                    int cs = colb ^ ((rowT & 7) << 3);
                    u16 hb = f2bf(ov[r]);
                    TH[rowT * 64 + cs] = hb;
                    TL[rowT * 64 + cs] = f2bf(ov[r] - bf2f(hb));
                }
            }
        }
        __builtin_amdgcn_sched_barrier(0);
#pragma unroll
        for (int it = 0; it < 8; it++) {
            int idx = lane + it * 64;
            int row = idx >> 3, colg = (idx & 7) * 8;
            int lo = row * 64 + (colg ^ ((row & 7) << 3));
            short8v vh = *(const short8v*)&TH[lo];
            short8v vl = *(const short8v*)&TL[lo];
            int mrow = row0 + wr * 64 + row;
            if (mrow < Mc) {
                *(short8v*)&PVH[(long)mrow * 256 + col0 + wc * 64 + colg] = vh;
                *(short8v*)&PVL[(long)mrow * 256 + col0 + wc * 64 + colg] = vl;
            }
        }
    }
}

// ---------------- pipelined 3-term out-proj GEMM ----------------
template <int ACT, int SPLITOUT>
__global__ __launch_bounds__(256) void gemm_out(
    const u16* __restrict__ AH, const u16* __restrict__ AL,
    const u16* __restrict__ BH, const u16* __restrict__ BL,
    const float* __restrict__ b1, const float* __restrict__ b2,
    float* __restrict__ C, u16* __restrict__ H1H,
    int Mc, int Nnodes, int nodeBase, int nwg) {
    __shared__ __attribute__((aligned(16))) u16 S[32768];
    int orig = blockIdx.y * 2 + blockIdx.x;
    int qq = nwg >> 3, rr = nwg & 7;
    int xcd = orig & 7, pos = orig >> 3;
    int wg = (xcd < rr ? xcd * (qq + 1) : rr * (qq + 1) + (xcd - rr) * qq) + pos;
    int bx = wg & 1, by = wg >> 1;
    int row0 = by * 128, col0 = bx * 128;
    int t = threadIdx.x, lane = t & 63, wv = t >> 6;

    int d0 = (wv * 2) * 64 + lane, d1 = d0 + 64;
    int row_0 = d0 >> 2, gp_0 = d0 & 3;
    int row_1 = d1 >> 2, gp_1 = d1 & 3;
    int sw_0 = (gp_0 ^ ((row_0 >> 1) & 3)) << 3;
    int sw_1 = (gp_1 ^ ((row_1 >> 1) & 3)) << 3;
    long arow0 = (long)(row0 + row_0) * 256 + sw_0;
    long arow1 = (long)(row0 + row_1) * 256 + sw_1;
    long brow0 = (long)(col0 + row_0) * 256 + sw_0;
    long brow1 = (long)(col0 + row_1) * 256 + sw_1;
    int base0 = wv * 1024, base1 = base0 + 512;

    int wr = wv >> 1, wc = wv & 1, lm = lane & 15, lk = lane >> 4;
    const int gsw = (lk ^ ((lm >> 1) & 3)) * 8;

    f32x4 acc[4][4];
#pragma unroll
    for (int i = 0; i < 4; i++)
#pragma unroll
        for (int j = 0; j < 4; j++) acc[i][j] = (f32x4)(0.f);

#define STAGE_O(db, k0)                                                \
    do {                                                               \
        gl2lds16(AH + arow0 + (k0), &S[(db) * 16384 + base0]);         \
        gl2lds16(AL + arow0 + (k0), &S[(db) * 16384 + 4096 + base0]);  \
        gl2lds16(BH + brow0 + (k0), &S[(db) * 16384 + 8192 + base0]);  \
        gl2lds16(BL + brow0 + (k0), &S[(db) * 16384 + 12288 + base0]); \
        gl2lds16(AH + arow1 + (k0), &S[(db) * 16384 + base1]);         \
        gl2lds16(AL + arow1 + (k0), &S[(db) * 16384 + 4096 + base1]);  \
        gl2lds16(BH + brow1 + (k0), &S[(db) * 16384 + 8192 + base1]);  \
        gl2lds16(BL + brow1 + (k0), &S[(db) * 16384 + 12288 + base1]); \
    } while (0)

    STAGE_O(0, 0);
    for (int ks = 0; ks < 8; ks++) {
        int cur = ks & 1;
        if (ks < 7) {
            STAGE_O(cur ^ 1, (ks + 1) * 32);
            asm volatile("s_waitcnt vmcnt(8)" ::: "memory");
        } else {
            asm volatile("s_waitcnt vmcnt(0)" ::: "memory");
        }
        __builtin_amdgcn_s_barrier();
        asm volatile("" ::: "memory");
        const u16* AhS = S + cur * 16384;
        const u16* AlS = AhS + 4096;
        const u16* BhS = AhS + 8192;
        const u16* BlS = AhS + 12288;
        short8v afh[4], afl[4], bfh[4], bfl[4];
#pragma unroll
        for (int i = 0; i < 4; i++) {
            int am_l = wr * 64 + i * 16 + lm;
            afh[i] = *(const short8v*)&AhS[am_l * 32 + gsw];
            afl[i] = *(const short8v*)&AlS[am_l * 32 + gsw];
            int bc_l = wc * 64 + i * 16 + lm;
            bfh[i] = *(const short8v*)&BhS[bc_l * 32 + gsw];
            bfl[i] = *(const short8v*)&BlS[bc_l * 32 + gsw];
        }
#pragma unroll
        for (int i = 0; i < 4; i++)
#pragma unroll
            for (int j = 0; j < 4; j++) {
                acc[i][j] = __builtin_amdgcn_mfma_f32_16x16x32_bf16(afh[i], bfh[j], acc[i][j], 0, 0, 0);
                acc[i][j] = __builtin_amdgcn_mfma_f32_16x16x32_bf16(afl[i], bfh[j], acc[i][j], 0, 0, 0);
                acc[i][j] = __builtin_amdgcn_mfma_f32_16x16x32_bf16(afh[i], bfl[j], acc[i][j], 0, 0, 0);
            }
        asm volatile("" ::: "memory");
        __builtin_amdgcn_s_barrier();
    }
#undef STAGE_O

    if (SPLITOUT) {
        u16* T = &S[wv * 4096];
#pragma unroll
        for (int i = 0; i < 4; i++)
#pragma unroll
            for (int j = 0; j < 4; j++) {
                int colb = j * 16 + lm;
                float bb = b1[col0 + wc * 64 + colb] + b2[col0 + wc * 64 + colb];
#pragma unroll
                for (int r = 0; r < 4; r++) {
                    int rowT = i * 16 + lk * 4 + r;
                    float v = acc[i][j][r] + bb;
                    if (ACT == 1) v = v > 0.f ? v : expm1f(v);
                    T[rowT * 64 + (colb ^ ((rowT & 7) << 3))] = f2bf(v);
                }
            }
        __builtin_amdgcn_sched_barrier(0);
#pragma unroll
        for (int it = 0; it < 8; it++) {
            int idx = lane + it * 64;
            int row = idx >> 3, colg = (idx & 7) * 8;
            short8v val = *(const short8v*)&T[row * 64 + (colg ^ ((row & 7) << 3))];
            int mrow = row0 + wr * 64 + row;
            if (mrow < Mc) {
                long cphys = (long)(mrow & 3) * Nnodes + nodeBase + (mrow >> 2);
                *(short8v*)&H1H[cphys * 256 + col0 + wc * 64 + colg] = val;
            }
        }
    } else {
#pragma unroll
        for (int i = 0; i < 4; i++) {
            int rowb = wr * 64 + i * 16 + lk * 4;
#pragma unroll
            for (int j = 0; j < 4; j++) {
                int col = col0 + wc * 64 + j * 16 + lm;
                float bb = b1[col] + b2[col];
#pragma unroll
                for (int r = 0; r < 4; r++) {
                    int m = row0 + rowb + r;
                    if (m >= Mc) continue;
                    long cphys = (long)(m & 3) * Nnodes + nodeBase + (m >> 2);
                    float v = acc[i][j][r] + bb;
                    if (ACT == 1) v = v > 0.f ? v : expm1f(v);
                    C[cphys * 256 + col] = v;
                }
            }
        }
    }
}

// ---------------- attention weights: one wave per node ----------------
__global__ __launch_bounds__(256) void aw_k(const u16* __restrict__ QK, float* __restrict__ aw, int chunkN) {
    int t = threadIdx.x, lane = t & 63, w = t >> 6;
    int node = blockIdx.x * 4 + w;
    if (node >= chunkN) return;
    int vq = lane >> 4, hd = (lane >> 2) & 3, vk = lane & 3;
    const u16* qp = QK + (long)(node * 4 + vq) * 512 + hd * 64;
    const u16* kp = QK + (long)(node * 4 + vk) * 512 + 256 + hd * 64;
    float acc = 0.f;
#pragma unroll
    for (int d0 = 0; d0 < 64; d0 += 8) {
        short8v qv = *(const short8v*)(qp + d0);
        short8v kv = *(const short8v*)(kp + d0);
#pragma unroll
        for (int j = 0; j < 8; j++) acc += bf2f((u16)qv[j]) * bf2f((u16)kv[j]);
    }
    float l = acc * 0.125f;
    float m = l;
    m = fmaxf(m, __shfl_xor(m, 1, 64));
    m = fmaxf(m, __shfl_xor(m, 2, 64));
    float e = expf(l - m);
    float s = e;
    s += __shfl_xor(s, 1, 64);
    s += __shfl_xor(s, 2, 64);
    aw[(long)node * 64 + hd * 16 + vq * 4 + vk] = e / s;
}

// ---------------- launcher ----------------

extern "C" void kernel_launch(void* const* d_in, const int* in_sizes, int n_in,
                              void* d_out, int out_size, void* d_ws, size_t ws_size,
                              hipStream_t stream) {
    const float* x = (const float*)d_in[0];
    const int* ei = (const int*)d_in[1];
    const float* W1 = (const float*)d_in[2];
    const float* att1 = (const float*)d_in[3];
    const float* qkv_w1 = (const float*)d_in[4];
    const float* qkv_b1 = (const float*)d_in[5];
    const float* out_w1 = (const float*)d_in[6];
    const float* out_b1 = (const float*)d_in[7];
    const float* bias1 = (const float*)d_in[8];
    const float* W2 = (const float*)d_in[9];
    const float* att2 = (const float*)d_in[10];
    const float* qkv_w2 = (const float*)d_in[11];
    const float* qkv_b2 = (const float*)d_in[12];
    const float* out_w2 = (const float*)d_in[13];
    const float* out_b2 = (const float*)d_in[14];
    const float* bias2 = (const float*)d_in[15];
    float* out = (float*)d_out;

    const int Nn = NN, E = EE, Etot = ETOT;
    const int MROWS = 40064;

    char* wsB = (char*)d_ws;
    size_t off = 0;
    auto alloc = [&](size_t bytes) -> void* {
        void* p = wsB + off;
        off += (bytes + 255) & ~(size_t)255;
        return p;
    };
    u16* W1TH = (u16*)alloc((size_t)256 * 64 * 2);
    u16* W1TL = (u16*)alloc((size_t)256 * 64 * 2);
    u16* W2TH = (u16*)alloc((size_t)256 * 256 * 2);
    u16* W2TL = (u16*)alloc((size_t)256 * 256 * 2);
    u16* qw1H = (u16*)alloc((size_t)768 * 256 * 2);
    u16* qw1L = (u16*)alloc((size_t)768 * 256 * 2);
    u16* qw2H = (u16*)alloc((size_t)768 * 256 * 2);
    u16* qw2L = (u16*)alloc((size_t)768 * 256 * 2);
    u16* ow1H = (u16*)alloc((size_t)256 * 256 * 2);
    u16* ow1L = (u16*)alloc((size_t)256 * 256 * 2);
    u16* ow2H = (u16*)alloc((size_t)256 * 256 * 2);
    u16* ow2L = (u16*)alloc((size_t)256 * 256 * 2);
    u16* xH = (u16*)alloc((size_t)MROWS * 64 * 2);
    u16* h1H = (u16*)alloc((size_t)MROWS * 256 * 2);
    u16* hbufB = (u16*)alloc((size_t)Nn * 4 * DD * 2);
    u16* aggH = (u16*)alloc((size_t)4 * NPAD * DD * 2);
    u16* aggL = (u16*)alloc((size_t)4 * NPAD * DD * 2);
    float* asrc = (float*)alloc((size_t)Nn * 4 * 4);
    float* adst = (float*)alloc((size_t)Nn * 4 * 4);
    float* wts = (float*)alloc((size_t)Etot * 4 * 4);
    float* hsum = (float*)alloc(4 * 4);
    float* pmax = (float*)alloc((size_t)256 * 4 * 4);
    int* deg = (int*)alloc((size_t)Nn * 4);
    int* offs = (int*)alloc((size_t)Nn * 4);
    int* cursor = (int*)alloc((size_t)Nn * 4);
    int* csr_eid = (int*)alloc((size_t)Etot * 4);
    int* csr_src = (int*)alloc((size_t)Etot * 4);

    auto aligned = [](size_t b) { return (b + 255) & ~(size_t)255; };
    auto mpad_of = [](int cN) { return ((cN * 4 + 127) / 128) * 128; };
    int nchunks = 40;
    {
        const int cands[8] = {1, 2, 4, 5, 8, 10, 20, 40};
        for (int ci = 0; ci < 8; ci++) {
            int cN = Nn / cands[ci];
            long mp = mpad_of(cN);
            size_t need = off + aligned((size_t)mp * 512 * 2) + 2 * aligned((size_t)mp * 256 * 2) +
                          aligned((size_t)(mp / 4) * 64 * 4);
            if (need <= ws_size) { nchunks = cands[ci]; break; }
        }
    }
    int chunkN = Nn / nchunks;
    int Mpad = mpad_of(chunkN);
    u16* QKb = (u16*)alloc((size_t)Mpad * 512 * 2);
    u16* PVH = (u16*)alloc((size_t)Mpad * 256 * 2);
    u16* PVL = (u16*)alloc((size_t)Mpad * 256 * 2);
    float* awb = (float*)alloc((size_t)(Mpad / 4) * 64 * 4);

    // --- prep ---
    transpose_split_k<<<(64 * 256 + 255) / 256, 256, 0, stream>>>(W1, W1TH, W1TL, 64, 256);
    transpose_split_k<<<(256 * 256 + 255) / 256, 256, 0, stream>>>(W2, W2TH, W2TL, 256, 256);
    split_k<<<(768 * 256 + 255) / 256, 256, 0, stream>>>(qkv_w1, qw1H, qw1L, 768 * 256);
    split_k<<<(768 * 256 + 255) / 256, 256, 0, stream>>>(qkv_w2, qw2H, qw2L, 768 * 256);
    split_k<<<(256 * 256 + 255) / 256, 256, 0, stream>>>(out_w1, ow1H, ow1L, 256 * 256);
    split_k<<<(256 * 256 + 255) / 256, 256, 0, stream>>>(out_w2, ow2H, ow2L, 256 * 256);
    cvt_k<<<(40000 * 64 + 255) / 256, 256, 0, stream>>>(x, xH, 40000 * 64);
    hipMemsetAsync(deg, 0, Nn * sizeof(int), stream);
    deg_k<<<(Etot + 255) / 256, 256, 0, stream>>>(ei, deg, E, Etot);
    scan_k<<<1, 1024, 0, stream>>>(deg, offs, cursor, Nn);
    csr_fill_k<<<(Etot + 255) / 256, 256, 0, stream>>>(ei, cursor, csr_eid, csr_src, E, Etot);

    auto scoresAndAgg = [&]() {
        edge_scores_max_k<<<256, 256, 0, stream>>>(ei, asrc, adst, wts, pmax, E, Etot);
        hipMemsetAsync(hsum, 0, 16, stream);
        exp_sum_k<<<(Etot * 4 + 255) / 256, 256, 0, stream>>>(wts, pmax, hsum, Etot * 4);
        agg3_k<<<Nn, 256, 0, stream>>>(hbufB, wts, offs, deg, csr_eid, csr_src, hsum, aggH, aggL, Nn);
    };

    int gy = Mpad / 128;

    // ---------------- layer 1 ----------------
    hipMemsetAsync(asrc, 0, (size_t)Nn * 4 * 4 * 2, stream);
    gemm_h<64><<<dim3(2, 313), 256, 0, stream>>>(xH, W1TH, hbufB, 40000, Nn, att1, asrc, adst, 626);
    scoresAndAgg();
    for (int c = 0; c < nchunks; c++) {
        int nb = c * chunkN;
        int Mc = chunkN * 4;
        gemm_qk<<<dim3(4, gy), 256, 0, stream>>>(aggH, qw1H, qkv_b1, QKb, Mc, nb, 4 * gy);
        aw_k<<<(chunkN + 3) / 4, 256, 0, stream>>>(QKb, awb, chunkN);
        gemm_vpv<<<dim3(2, gy), 256, 0, stream>>>(aggH, aggL, qw1H + 512 * 256, qw1L + 512 * 256,
                                                  qkv_b1 + 512, awb, PVH, PVL, Mc, nb, 2 * gy);
        gemm_out<1, 1><<<dim3(2, gy), 256, 0, stream>>>(PVH, PVL, ow1H, ow1L, out_b1, bias1,
                                                        nullptr, h1H, Mc, Nn, nb, 2 * gy);
    }

    // ---------------- layer 2 ----------------
    hipMemsetAsync(asrc, 0, (size_t)Nn * 4 * 4 * 2, stream);
    gemm_h<256><<<dim3(2, 313), 256, 0, stream>>>(h1H, W2TH, hbufB, 40000, Nn, att2, asrc, adst, 626);
    scoresAndAgg();
    for (int c = 0; c < nchunks; c++) {
        int nb = c * chunkN;
        int Mc = chunkN * 4;
        gemm_qk<<<dim3(4, gy), 256, 0, stream>>>(aggH, qw2H, qkv_b2, QKb, Mc, nb, 4 * gy);
        aw_k<<<(chunkN + 3) / 4, 256, 0, stream>>>(QKb, awb, chunkN);
        gemm_vpv<<<dim3(2, gy), 256, 0, stream>>>(aggH, aggL, qw2H + 512 * 256, qw2L + 512 * 256,
                                                  qkv_b2 + 512, awb, PVH, PVL, Mc, nb, 2 * gy);
        gemm_out<0, 0><<<dim3(2, gy), 256, 0, stream>>>(PVH, PVL, ow2H, ow2L, out_b2, bias2,
                                                        out, nullptr, Mc, Nn, nb, 2 * gy);
    }
}